// Round 12
// baseline (252.900 us; speedup 1.0000x reference)
//
#include <hip/hip_runtime.h>
#include <math.h>

#define N_NODES   100000
#define N_EDGES   1600000
#define VOCAB     2048
#define NODE_DIM  64
#define HIDDEN    64
#define N_MASK    10000

#define BN        48             // nodes per bucket (2084 blocks x 4 waves -> fine-grain packing)
#define NBKT      2084           // ceil(100000/48)
#define CHUNK     4096           // edges per partition block
#define NCH       391            // ceil(N_EDGES/CHUNK)
#define ELCAP     1024           // LDS edge capacity per bucket (mean 768, sigma 28 -> +9σ)

typedef __attribute__((ext_vector_type(8))) short short8;
typedef __attribute__((ext_vector_type(4))) float f32x4;
typedef unsigned short ushort_t;
typedef unsigned int uint_t;

// ---------------- workspace layout (bytes), 16-aligned ----------------
#define H1_OFF      0            // 100000*64 f32  = 25,600,000
#define ESRC_OFF    25600000     // 1.6M i32       =  6,400,000  (CSR order)
#define E2_OFF      32000000     // 1.6M int2      = 12,800,000
#define EWL_OFF     44800000     //   2048*64 f32  =    524,288
#define EWR_OFF     45324288     //   2048*64 f32  =    524,288
#define W2T_OFF     45848576     //   2048*128 bf16=    524,288
#define X2B_OFF     46372864     //   10000*128 bf16= 2,560,000
#define ROWPTR_OFF  48932864     // 100001 i32     =    400,004
#define BCNT_OFF    49332880     // 2084 i32       =      8,336
#define BPTR_OFF    49341216     // 2085 i32       =      8,340
#define MAT_OFF     49349568     // NCH*NBKT u16   =  1,629,688
// total ~50.98 MB (within proven footprint)

__device__ __forceinline__ ushort_t f2bf(float f) {
    uint_t u = __builtin_bit_cast(uint_t, f);
    u += 0x7FFFu + ((u >> 16) & 1u);        // round-to-nearest-even
    return (ushort_t)(u >> 16);
}

// one launch for all launch-ready work:
// blocks [0,512):      embWl = emb @ Wl1
// blocks [512,1024):   embWr = emb @ Wr1
// blocks [1024,1088):  W2T[n][k] = bf16([Wl2;Wr2]^T)
// blocks [1088,1479):  per-chunk bucket histogram -> mat row (u16), no atomics
__global__ __launch_bounds__(256) void k_prep(const float* __restrict__ emb,
                                              const float* __restrict__ Wl1,
                                              const float* __restrict__ Wr1,
                                              const float* __restrict__ Wl2,
                                              const float* __restrict__ Wr2,
                                              const int* __restrict__ dst,
                                              float* __restrict__ embWl,
                                              float* __restrict__ embWr,
                                              ushort_t* __restrict__ W2T,
                                              ushort_t* __restrict__ mat) {
    __shared__ ushort_t T[64 * 66];
    __shared__ int hist[NBKT];
    const int bx = blockIdx.x;
    const int tid = threadIdx.x;
    if (bx < 1024) {
        const int half = bx >> 9;
        const float* W = half ? Wr1 : Wl1;
        float* out = half ? embWr : embWl;
        int idx = (bx & 511) * 256 + tid;
        int v = idx >> 6, c = idx & 63;
        float s = 0.0f;
#pragma unroll 8
        for (int k = 0; k < 64; k++) s += emb[v * 64 + k] * W[k * 64 + c];
        out[idx] = s;
    } else if (bx < 1088) {
        int t = bx - 1024;                    // 64 blocks: 2 k-halves x 32 n-tiles
        const int k0 = (t & 1) * 64;
        const int n0 = (t >> 1) * 64;
        const float* Wsrc = (k0 == 0) ? Wl2 : Wr2;
#pragma unroll
        for (int i = 0; i < 16; i++) {
            int idx = i * 256 + tid;
            int k = idx >> 6, n = idx & 63;
            T[n * 66 + k] = f2bf(Wsrc[(size_t)k * VOCAB + n0 + n]);
        }
        __syncthreads();
#pragma unroll
        for (int i = 0; i < 16; i++) {
            int idx = i * 256 + tid;
            int n = idx >> 6, k = idx & 63;
            W2T[(size_t)(n0 + n) * 128 + k0 + k] = T[n * 66 + k];
        }
    } else {
        const int c = bx - 1088;
        const int e0 = c * CHUNK;
        const int n = min(CHUNK, N_EDGES - e0);
        for (int i = tid; i < NBKT; i += 256) hist[i] = 0;
        int d[16];
#pragma unroll
        for (int i = 0; i < 16; i++) {
            int idx = i * 256 + tid;
            d[i] = (idx < n) ? dst[e0 + idx] : -1;    // all loads in flight early
        }
        __syncthreads();
#pragma unroll
        for (int i = 0; i < 16; i++)
            if (d[i] >= 0) atomicAdd(&hist[d[i] / BN], 1);
        __syncthreads();
        for (int i = tid; i < NBKT; i += 256) mat[(size_t)c * NBKT + i] = (ushort_t)hist[i];
    }
}

// per-bucket column scan of the count matrix (NCH=391 entries, 512-thread
// scan): mat[c][b] becomes the within-bucket exclusive offset of chunk c;
// bucket total -> bcnt[b].
__global__ __launch_bounds__(512) void k_mscan(ushort_t* __restrict__ mat,
                                               int* __restrict__ bcnt) {
    __shared__ int s[512];
    const int b = blockIdx.x, t = threadIdx.x;
    int v = (t < NCH) ? (int)mat[(size_t)t * NBKT + b] : 0;
    s[t] = v;
    __syncthreads();
    for (int off = 1; off < 512; off <<= 1) {
        int a = (t >= off) ? s[t - off] : 0;
        __syncthreads();
        s[t] += a;
        __syncthreads();
    }
    if (t < NCH) mat[(size_t)t * NBKT + b] = (ushort_t)(s[t] - v);   // exclusive
    if (t == NCH - 1) bcnt[b] = s[t];
}

// exclusive scan of 2084 bucket counts (3 per thread) -> bptr; rowptr[N] = N_EDGES
__global__ __launch_bounds__(1024) void k_bscan(const int* __restrict__ bcnt,
                                                int* __restrict__ bptr,
                                                int* __restrict__ rowptr) {
    __shared__ int s[1024];
    int t = threadIdx.x;
    int i0 = 3 * t;
    int a0 = (i0     < NBKT) ? bcnt[i0]     : 0;
    int a1 = (i0 + 1 < NBKT) ? bcnt[i0 + 1] : 0;
    int a2 = (i0 + 2 < NBKT) ? bcnt[i0 + 2] : 0;
    int v = a0 + a1 + a2;
    s[t] = v;
    __syncthreads();
    for (int off = 1; off < 1024; off <<= 1) {
        int p = (t >= off) ? s[t - off] : 0;
        __syncthreads();
        s[t] += p;
        __syncthreads();
    }
    int excl = s[t] - v;
    if (i0     < NBKT) bptr[i0]     = excl;
    if (i0 + 1 < NBKT) bptr[i0 + 1] = excl + a0;
    if (i0 + 2 < NBKT) bptr[i0 + 2] = excl + a0 + a1;
    if (t == 1023) bptr[NBKT] = s[t];          // = N_EDGES
    if (t == 0) rowptr[N_NODES] = N_EDGES;
}

// partition edges into bucket-contiguous e2 = (src, voc<<8 | dst%BN).
// Deterministic cursors (bptr + matrix prefix) -> LDS atomics ONLY.
__global__ __launch_bounds__(256) void k_scatter3(const int* __restrict__ src,
                                                  const int* __restrict__ dst,
                                                  const int* __restrict__ x,
                                                  const ushort_t* __restrict__ mat,
                                                  const int* __restrict__ bptr,
                                                  int2* __restrict__ e2) {
    __shared__ int cur[NBKT];
    const int c = blockIdx.x, t = threadIdx.x;
    const int e0 = c * CHUNK;
    const int n = min(CHUNK, N_EDGES - e0);
    for (int i = t; i < NBKT; i += 256)
        cur[i] = bptr[i] + (int)mat[(size_t)c * NBKT + i];
    int d[16], sv[16], voc[16];
#pragma unroll
    for (int i = 0; i < 16; i++) {
        int idx = i * 256 + t;
        if (idx < n) { d[i] = dst[e0 + idx]; sv[i] = src[e0 + idx]; }
        else d[i] = -1;
    }
#pragma unroll
    for (int i = 0; i < 16; i++)
        if (d[i] >= 0) voc[i] = x[sv[i]];          // gathers in flight early
    __syncthreads();
#pragma unroll
    for (int i = 0; i < 16; i++) {
        if (d[i] >= 0) {
            int b = d[i] / BN;                     // compile-time magic-mul
            int pos = atomicAdd(&cur[b], 1);
            e2[pos] = make_int2(sv[i], (voc[i] << 8) | (d[i] - b * BN));
        }
    }
}

// FUSED per-bucket counting sort + layer-1 aggregation (r5 internal
// structure, BN=48 / 256-thread geometry for fine-grain CU packing).
// h1[n] = relu( mean_e embWl[voc_e] + embWr[x[n]] + b1 ).
__global__ __launch_bounds__(256) void k_sortagg(const int* __restrict__ bptr,
                                                 const int2* __restrict__ e2,
                                                 const int* __restrict__ x,
                                                 const float* __restrict__ embWl,
                                                 const float* __restrict__ embWr,
                                                 const float* __restrict__ b1,
                                                 int* __restrict__ rowptr,
                                                 int* __restrict__ esrc,
                                                 float* __restrict__ h1) {
    __shared__ int2 eL[ELCAP];          // 8 KB sorted edge staging
    __shared__ int sc[64];              // scan workspace (BN=48 <= 64)
    __shared__ int cur[BN];             // scatter cursors
    __shared__ int base[BN + 1];        // exclusive offsets (stable copy)
    const int b = blockIdx.x;
    const int t = threadIdx.x;
    const int r0 = bptr[b], r1 = bptr[b + 1];
    const int m = r1 - r0;

    // stage this block's edges ONCE (coalesced, up to 4/thread in registers)
    int2 ev[4];
#pragma unroll
    for (int k = 0; k < 4; k++) {
        int i = r0 + t + k * 256;
        ev[k] = (i < r1) ? e2[i] : make_int2(-1, 0);   // .x=-1 sentinel
    }
    if (t < 64) sc[t] = 0;
    __syncthreads();

    // histogram per local node (from registers)
#pragma unroll
    for (int k = 0; k < 4; k++)
        if (ev[k].x >= 0) atomicAdd(&sc[ev[k].y & 255], 1);
    __syncthreads();
    // inclusive scan (64 entries; all threads hit barriers)
    int v = (t < 64) ? sc[t] : 0;
    for (int off = 1; off < 64; off <<= 1) {
        int a = (t >= off && t < 64) ? sc[t - off] : 0;
        __syncthreads();
        if (t < 64) sc[t] += a;
        __syncthreads();
    }
    if (t < BN) {
        int excl = sc[t] - v;
        base[t] = excl;
        cur[t] = excl;
        int node = b * BN + t;
        if (node < N_NODES) rowptr[node] = r0 + excl;
        if (t == BN - 1) base[BN] = sc[t];    // = m
    }
    __syncthreads();
    // counting-sort scatter into LDS (from registers — no 2nd global pass)
#pragma unroll
    for (int k = 0; k < 4; k++) {
        if (ev[k].x >= 0) {
            int pos = atomicAdd(&cur[ev[k].y & 255], 1);
            eL[pos] = ev[k];
        }
    }
    __syncthreads();
    // CSR src write, fully coalesced from sorted LDS
    for (int i = t; i < m; i += 256)
        esrc[r0 + i] = eL[i].x;

    // per-node aggregation: 4 waves round-robin the 48 nodes; descriptors
    // come from LDS via wave-uniform broadcast reads; 8 gathers in flight.
    const int wv = t >> 6, lane = t & 63;
    const float b1v = b1[lane];
    for (int nl = wv; nl < BN; nl += 4) {
        int node = b * BN + nl;
        if (node >= N_NODES) break;
        int j0 = base[nl], j1 = base[nl + 1];
        int deg = j1 - j0;
        float s0 = 0.f, s1 = 0.f, s2 = 0.f, s3 = 0.f;
        float s4 = 0.f, s5 = 0.f, s6 = 0.f, s7 = 0.f;
        int j = j0;
        for (; j + 7 < j1; j += 8) {
            int y0 = eL[j].y,     y1 = eL[j + 1].y, y2 = eL[j + 2].y, y3 = eL[j + 3].y;
            int y4 = eL[j + 4].y, y5 = eL[j + 5].y, y6 = eL[j + 6].y, y7 = eL[j + 7].y;
            s0 += embWl[((y0 >> 8) << 6) + lane];
            s1 += embWl[((y1 >> 8) << 6) + lane];
            s2 += embWl[((y2 >> 8) << 6) + lane];
            s3 += embWl[((y3 >> 8) << 6) + lane];
            s4 += embWl[((y4 >> 8) << 6) + lane];
            s5 += embWl[((y5 >> 8) << 6) + lane];
            s6 += embWl[((y6 >> 8) << 6) + lane];
            s7 += embWl[((y7 >> 8) << 6) + lane];
        }
        for (; j + 3 < j1; j += 4) {
            int y0 = eL[j].y, y1 = eL[j + 1].y, y2 = eL[j + 2].y, y3 = eL[j + 3].y;
            s0 += embWl[((y0 >> 8) << 6) + lane];
            s1 += embWl[((y1 >> 8) << 6) + lane];
            s2 += embWl[((y2 >> 8) << 6) + lane];
            s3 += embWl[((y3 >> 8) << 6) + lane];
        }
        for (; j < j1; j++)
            s0 += embWl[((eL[j].y >> 8) << 6) + lane];
        float sum = ((s0 + s1) + (s2 + s3)) + ((s4 + s5) + (s6 + s7));
        float inv = 1.0f / fmaxf((float)deg, 1.0f);
        float self = embWr[(x[node] << 6) + lane];
        h1[((size_t)node << 6) + lane] = fmaxf(sum * inv + self + b1v, 0.0f);
    }
}

// X2b[m] = bf16[ mean_e h1[src_e] | h1[mask[m]] ], one wave per masked row,
// 8 gathers in flight.
__global__ __launch_bounds__(256) void k_x2(const int* __restrict__ mask,
                                            const int* __restrict__ rowptr,
                                            const int* __restrict__ esrc,
                                            const float* __restrict__ h1,
                                            ushort_t* __restrict__ X2b) {
    int gw = (blockIdx.x * 256 + threadIdx.x) >> 6;
    int lane = threadIdx.x & 63;
    if (gw >= N_MASK) return;
    int n = mask[gw];
    int r0 = rowptr[n], r1 = rowptr[n + 1];
    int deg = r1 - r0;
    float s0 = 0.f, s1 = 0.f, s2 = 0.f, s3 = 0.f;
    float s4 = 0.f, s5 = 0.f, s6 = 0.f, s7 = 0.f;
    for (int base = 0; base < deg; base += 64) {
        int cnt = min(64, deg - base);
        int mys = (base + lane < deg) ? esrc[r0 + base + lane] : 0;
        int t = 0;
        for (; t + 7 < cnt; t += 8) {
            int sa = __shfl(mys, t),     sb = __shfl(mys, t + 1);
            int sc = __shfl(mys, t + 2), sd = __shfl(mys, t + 3);
            int se = __shfl(mys, t + 4), sf = __shfl(mys, t + 5);
            int sg = __shfl(mys, t + 6), sh = __shfl(mys, t + 7);
            s0 += h1[((size_t)sa << 6) + lane];
            s1 += h1[((size_t)sb << 6) + lane];
            s2 += h1[((size_t)sc << 6) + lane];
            s3 += h1[((size_t)sd << 6) + lane];
            s4 += h1[((size_t)se << 6) + lane];
            s5 += h1[((size_t)sf << 6) + lane];
            s6 += h1[((size_t)sg << 6) + lane];
            s7 += h1[((size_t)sh << 6) + lane];
        }
        for (; t + 3 < cnt; t += 4) {
            int sa = __shfl(mys, t),     sb = __shfl(mys, t + 1);
            int sc = __shfl(mys, t + 2), sd = __shfl(mys, t + 3);
            s0 += h1[((size_t)sa << 6) + lane];
            s1 += h1[((size_t)sb << 6) + lane];
            s2 += h1[((size_t)sc << 6) + lane];
            s3 += h1[((size_t)sd << 6) + lane];
        }
        for (; t < cnt; t++)
            s0 += h1[((size_t)__shfl(mys, t) << 6) + lane];
    }
    float sum = ((s0 + s1) + (s2 + s3)) + ((s4 + s5) + (s6 + s7));
    float inv = 1.0f / fmaxf((float)deg, 1.0f);
    X2b[gw * 128 + lane]      = f2bf(sum * inv);
    X2b[gw * 128 + 64 + lane] = f2bf(h1[((size_t)n << 6) + lane]);
}

// out[R][c] = b2[c] + X2[R] . W2T[c]   via bf16 MFMA, fp32 accumulate.
__global__ __launch_bounds__(256) void k_gemm2_mfma(const ushort_t* __restrict__ X2b,
                                                    const ushort_t* __restrict__ W2T,
                                                    const float* __restrict__ bias,
                                                    float* __restrict__ out,
                                                    int M) {
    __shared__ ushort_t As[64 * 144];
    __shared__ ushort_t Bs[64 * 144];
    const int tid  = threadIdx.x;
    const int row0 = blockIdx.x * 64;
    const int col0 = blockIdx.y * 64;

#pragma unroll
    for (int i = 0; i < 4; i++) {
        int idx = i * 256 + tid;
        int r = idx >> 4, ch = idx & 15;
        int R = row0 + r;
        short8 v = {0, 0, 0, 0, 0, 0, 0, 0};
        if (R < M) v = *(const short8*)(X2b + (size_t)R * 128 + ch * 8);
        *(short8*)(As + r * 144 + ch * 8) = v;
    }
#pragma unroll
    for (int i = 0; i < 4; i++) {
        int idx = i * 256 + tid;
        int r = idx >> 4, ch = idx & 15;
        *(short8*)(Bs + r * 144 + ch * 8) =
            *(const short8*)(W2T + (size_t)(col0 + r) * 128 + ch * 8);
    }
    __syncthreads();

    const int lane = tid & 63;
    const int wv   = tid >> 6;
    const int wr = wv >> 1, wc = wv & 1;
    const int l15 = lane & 15, q = lane >> 4;

    f32x4 acc[2][2] = {};
    const ushort_t* Abase = As + (wr * 32 + l15) * 144 + q * 8;
    const ushort_t* Bbase = Bs + (wc * 32 + l15) * 144 + q * 8;

#pragma unroll
    for (int ks = 0; ks < 4; ks++) {
        short8 a0 = *(const short8*)(Abase + ks * 32);
        short8 a1 = *(const short8*)(Abase + 16 * 144 + ks * 32);
        short8 b0 = *(const short8*)(Bbase + ks * 32);
        short8 b1 = *(const short8*)(Bbase + 16 * 144 + ks * 32);
        acc[0][0] = __builtin_amdgcn_mfma_f32_16x16x32_bf16(a0, b0, acc[0][0], 0, 0, 0);
        acc[0][1] = __builtin_amdgcn_mfma_f32_16x16x32_bf16(a0, b1, acc[0][1], 0, 0, 0);
        acc[1][0] = __builtin_amdgcn_mfma_f32_16x16x32_bf16(a1, b0, acc[1][0], 0, 0, 0);
        acc[1][1] = __builtin_amdgcn_mfma_f32_16x16x32_bf16(a1, b1, acc[1][1], 0, 0, 0);
    }

    // C/D layout: col = lane&15, row = (lane>>4)*4 + reg  [verified m89/m91]
#pragma unroll
    for (int ni = 0; ni < 2; ni++) {
        int c_ = col0 + wc * 32 + ni * 16 + l15;
        float bv = bias[c_];
#pragma unroll
        for (int mi = 0; mi < 2; mi++) {
#pragma unroll
            for (int reg = 0; reg < 4; reg++) {
                int r_ = row0 + wr * 32 + mi * 16 + q * 4 + reg;
                if (r_ < M) out[(size_t)r_ * VOCAB + c_] = acc[mi][ni][reg] + bv;
            }
        }
    }
}

__global__ __launch_bounds__(256) void k_logsoftmax(float* __restrict__ out) {
    const int row = blockIdx.x;
    float4* p4 = (float4*)(out + (size_t)row * VOCAB);
    const int tid = threadIdx.x;
    float4 v[2];
    float m = -INFINITY;
#pragma unroll
    for (int i = 0; i < 2; i++) {
        v[i] = p4[tid + i * 256];
        m = fmaxf(m, fmaxf(fmaxf(v[i].x, v[i].y), fmaxf(v[i].z, v[i].w)));
    }
#pragma unroll
    for (int off = 1; off < 64; off <<= 1) m = fmaxf(m, __shfl_xor(m, off));
    __shared__ float redm[4];
    __shared__ float reds[4];
    int wave = tid >> 6;
    if ((tid & 63) == 0) redm[wave] = m;
    __syncthreads();
    m = fmaxf(fmaxf(redm[0], redm[1]), fmaxf(redm[2], redm[3]));
    float s = 0.0f;
#pragma unroll
    for (int i = 0; i < 2; i++)
        s += expf(v[i].x - m) + expf(v[i].y - m) + expf(v[i].z - m) + expf(v[i].w - m);
#pragma unroll
    for (int off = 1; off < 64; off <<= 1) s += __shfl_xor(s, off);
    if ((tid & 63) == 0) reds[wave] = s;
    __syncthreads();
    s = reds[0] + reds[1] + reds[2] + reds[3];
    float L = m + logf(s);
#pragma unroll
    for (int i = 0; i < 2; i++) {
        float4 o = v[i];
        o.x -= L; o.y -= L; o.z -= L; o.w -= L;
        p4[tid + i * 256] = o;
    }
}

extern "C" void kernel_launch(void* const* d_in, const int* in_sizes, int n_in,
                              void* d_out, int out_size, void* d_ws, size_t ws_size,
                              hipStream_t stream) {
    const int*   x    = (const int*)d_in[0];
    const int*   ei   = (const int*)d_in[1];
    const int*   src  = ei;
    const int*   dst  = ei + N_EDGES;
    const int*   mask = (const int*)d_in[2];
    const float* emb  = (const float*)d_in[3];
    const float* Wl1  = (const float*)d_in[4];
    const float* bl1  = (const float*)d_in[5];
    const float* Wr1  = (const float*)d_in[6];
    const float* Wl2  = (const float*)d_in[7];
    const float* bl2  = (const float*)d_in[8];
    const float* Wr2  = (const float*)d_in[9];
    float* out = (float*)d_out;

    char* ws = (char*)d_ws;
    float*    h1     = (float*)(ws + H1_OFF);
    int*      esrc   = (int*)(ws + ESRC_OFF);
    int2*     e2     = (int2*)(ws + E2_OFF);
    float*    embWl  = (float*)(ws + EWL_OFF);
    float*    embWr  = (float*)(ws + EWR_OFF);
    ushort_t* W2T    = (ushort_t*)(ws + W2T_OFF);
    ushort_t* X2b    = (ushort_t*)(ws + X2B_OFF);
    int*      rowptr = (int*)(ws + ROWPTR_OFF);
    int*      bcnt   = (int*)(ws + BCNT_OFF);
    int*      bptr   = (int*)(ws + BPTR_OFF);
    ushort_t* mat    = (ushort_t*)(ws + MAT_OFF);

    // ---- tables + per-chunk histograms in ONE launch (all inputs ready) ----
    k_prep<<<1088 + NCH, 256, 0, stream>>>(emb, Wl1, Wr1, Wl2, Wr2, dst,
                                           embWl, embWr, W2T, mat);

    // ---- deterministic count-matrix partition (no global atomics) ----
    k_mscan   <<<NBKT, 512, 0, stream>>>(mat, bcnt);
    k_bscan   <<<1, 1024, 0, stream>>>(bcnt, bptr, rowptr);
    k_scatter3<<<NCH, 256, 0, stream>>>(src, dst, x, mat, bptr, e2);

    // ---- fused per-bucket sort + layer-1 aggregation (single e2 pass) ----
    k_sortagg<<<NBKT, 256, 0, stream>>>(bptr, e2, x, embWl, embWr, bl1, rowptr, esrc, h1);

    // ---- layer 2: masked-row gather -> bf16 X2, MFMA GEMM, log_softmax ----
    k_x2<<<(N_MASK * 64 + 255) / 256, 256, 0, stream>>>(mask, rowptr, esrc, h1, X2b);
    dim3 g2((N_MASK + 63) / 64, VOCAB / 64);
    k_gemm2_mfma<<<g2, 256, 0, stream>>>(X2b, W2T, bl2, out, N_MASK);

    k_logsoftmax<<<N_MASK, 256, 0, stream>>>(out);
}

// Round 13
// 244.840 us; speedup vs baseline: 1.0329x; 1.0329x over previous
//
#include <hip/hip_runtime.h>
#include <math.h>

#define N_NODES   100000
#define N_EDGES   1600000
#define VOCAB     2048
#define NODE_DIM  64
#define HIDDEN    64
#define N_MASK    10000

#define BN        96             // nodes per bucket (1042 blocks ~ 4/CU in sortagg)
#define NBKT      1042           // ceil(100000/96)
#define CHUNK     4096           // edges per partition block (deterministic cursors -> big chunks fine)
#define NCH       391            // ceil(N_EDGES/CHUNK)
#define ELCAP     2048           // LDS edge capacity per bucket (mean 1536, sigma 39)

typedef __attribute__((ext_vector_type(8))) short short8;
typedef __attribute__((ext_vector_type(4))) float f32x4;
typedef unsigned short ushort_t;
typedef unsigned int uint_t;

// ---------------- workspace layout (bytes), 16-aligned ----------------
#define H1_OFF      0            // 100000*64 f32  = 25,600,000
#define ESRC_OFF    25600000     // 1.6M i32       =  6,400,000  (CSR order)
#define E2_OFF      32000000     // 1.6M int2      = 12,800,000
#define EWL_OFF     44800000     //   2048*64 f32  =    524,288
#define EWR_OFF     45324288     //   2048*64 f32  =    524,288
#define W2T_OFF     45848576     //   2048*128 bf16=    524,288
#define X2B_OFF     46372864     //   10000*128 bf16= 2,560,000
#define ROWPTR_OFF  48932864     // 100001 i32     =    400,004
#define BCNT_OFF    49332880     // 1042 i32       =      4,168
#define BPTR_OFF    49337056     // 1043 i32       =      4,172
#define MAT_OFF     49341232     // NCH*NBKT u16   =    814,844
// total ~50.16 MB (within proven footprint)

__device__ __forceinline__ ushort_t f2bf(float f) {
    uint_t u = __builtin_bit_cast(uint_t, f);
    u += 0x7FFFu + ((u >> 16) & 1u);        // round-to-nearest-even
    return (ushort_t)(u >> 16);
}

// one launch for all launch-ready work (saves a launch; count2's histogram
// latency overlaps the table GEMMs):
// blocks [0,512):      embWl = emb @ Wl1
// blocks [512,1024):   embWr = emb @ Wr1
// blocks [1024,1088):  W2T[n][k] = bf16([Wl2;Wr2]^T)
// blocks [1088,1479):  per-chunk bucket histogram -> mat row (u16), no atomics
__global__ __launch_bounds__(256) void k_prep(const float* __restrict__ emb,
                                              const float* __restrict__ Wl1,
                                              const float* __restrict__ Wr1,
                                              const float* __restrict__ Wl2,
                                              const float* __restrict__ Wr2,
                                              const int* __restrict__ dst,
                                              float* __restrict__ embWl,
                                              float* __restrict__ embWr,
                                              ushort_t* __restrict__ W2T,
                                              ushort_t* __restrict__ mat) {
    __shared__ ushort_t T[64 * 66];
    __shared__ int hist[NBKT];
    const int bx = blockIdx.x;
    const int tid = threadIdx.x;
    if (bx < 1024) {
        const int half = bx >> 9;
        const float* W = half ? Wr1 : Wl1;
        float* out = half ? embWr : embWl;
        int idx = (bx & 511) * 256 + tid;
        int v = idx >> 6, c = idx & 63;
        float s = 0.0f;
#pragma unroll 8
        for (int k = 0; k < 64; k++) s += emb[v * 64 + k] * W[k * 64 + c];
        out[idx] = s;
    } else if (bx < 1088) {
        int t = bx - 1024;                    // 64 blocks: 2 k-halves x 32 n-tiles
        const int k0 = (t & 1) * 64;
        const int n0 = (t >> 1) * 64;
        const float* Wsrc = (k0 == 0) ? Wl2 : Wr2;
#pragma unroll
        for (int i = 0; i < 16; i++) {
            int idx = i * 256 + tid;
            int k = idx >> 6, n = idx & 63;
            T[n * 66 + k] = f2bf(Wsrc[(size_t)k * VOCAB + n0 + n]);
        }
        __syncthreads();
#pragma unroll
        for (int i = 0; i < 16; i++) {
            int idx = i * 256 + tid;
            int n = idx >> 6, k = idx & 63;
            W2T[(size_t)(n0 + n) * 128 + k0 + k] = T[n * 66 + k];
        }
    } else {
        const int c = bx - 1088;
        const int e0 = c * CHUNK;
        const int n = min(CHUNK, N_EDGES - e0);
        for (int i = tid; i < NBKT; i += 256) hist[i] = 0;
        int d[16];
#pragma unroll
        for (int i = 0; i < 16; i++) {
            int idx = i * 256 + tid;
            d[i] = (idx < n) ? dst[e0 + idx] : -1;    // all loads in flight early
        }
        __syncthreads();
#pragma unroll
        for (int i = 0; i < 16; i++)
            if (d[i] >= 0) atomicAdd(&hist[d[i] / BN], 1);
        __syncthreads();
        for (int i = tid; i < NBKT; i += 256) mat[(size_t)c * NBKT + i] = (ushort_t)hist[i];
    }
}

// per-bucket column scan of the count matrix (NCH=391 entries, 512-thread
// scan): mat[c][b] becomes the within-bucket exclusive offset of chunk c;
// bucket total -> bcnt[b].
__global__ __launch_bounds__(512) void k_mscan(ushort_t* __restrict__ mat,
                                               int* __restrict__ bcnt) {
    __shared__ int s[512];
    const int b = blockIdx.x, t = threadIdx.x;
    int v = (t < NCH) ? (int)mat[(size_t)t * NBKT + b] : 0;
    s[t] = v;
    __syncthreads();
    for (int off = 1; off < 512; off <<= 1) {
        int a = (t >= off) ? s[t - off] : 0;
        __syncthreads();
        s[t] += a;
        __syncthreads();
    }
    if (t < NCH) mat[(size_t)t * NBKT + b] = (ushort_t)(s[t] - v);   // exclusive
    if (t == NCH - 1) bcnt[b] = s[t];
}

// exclusive scan of 1042 bucket counts (2 per thread) -> bptr; rowptr[N] = N_EDGES
__global__ __launch_bounds__(1024) void k_bscan(const int* __restrict__ bcnt,
                                                int* __restrict__ bptr,
                                                int* __restrict__ rowptr) {
    __shared__ int s[1024];
    int t = threadIdx.x;
    int i0 = 2 * t, i1 = 2 * t + 1;
    int a = (i0 < NBKT) ? bcnt[i0] : 0;
    int b = (i1 < NBKT) ? bcnt[i1] : 0;
    int v = a + b;
    s[t] = v;
    __syncthreads();
    for (int off = 1; off < 1024; off <<= 1) {
        int p = (t >= off) ? s[t - off] : 0;
        __syncthreads();
        s[t] += p;
        __syncthreads();
    }
    int excl = s[t] - v;
    if (i0 < NBKT) bptr[i0] = excl;
    if (i1 < NBKT) bptr[i1] = excl + a;
    if (t == 1023) bptr[NBKT] = s[t];          // = N_EDGES
    if (t == 0) rowptr[N_NODES] = N_EDGES;
}

// partition edges into bucket-contiguous e2 = (src, voc<<8 | dst%BN).
// Deterministic cursors (bptr + matrix prefix) -> LDS atomics ONLY.
// CHUNK=4096: 391 blocks, cursor-init work halved vs CHUNK=2048.
__global__ __launch_bounds__(256) void k_scatter3(const int* __restrict__ src,
                                                  const int* __restrict__ dst,
                                                  const int* __restrict__ x,
                                                  const ushort_t* __restrict__ mat,
                                                  const int* __restrict__ bptr,
                                                  int2* __restrict__ e2) {
    __shared__ int cur[NBKT];
    const int c = blockIdx.x, t = threadIdx.x;
    const int e0 = c * CHUNK;
    const int n = min(CHUNK, N_EDGES - e0);
    for (int i = t; i < NBKT; i += 256)
        cur[i] = bptr[i] + (int)mat[(size_t)c * NBKT + i];
    int d[16], sv[16], voc[16];
#pragma unroll
    for (int i = 0; i < 16; i++) {
        int idx = i * 256 + t;
        if (idx < n) { d[i] = dst[e0 + idx]; sv[i] = src[e0 + idx]; }
        else d[i] = -1;
    }
#pragma unroll
    for (int i = 0; i < 16; i++)
        if (d[i] >= 0) voc[i] = x[sv[i]];          // gathers in flight early
    __syncthreads();
#pragma unroll
    for (int i = 0; i < 16; i++) {
        if (d[i] >= 0) {
            int b = d[i] / BN;                     // compile-time magic-mul
            int pos = atomicAdd(&cur[b], 1);
            e2[pos] = make_int2(sv[i], (voc[i] << 8) | (d[i] - b * BN));
        }
    }
}

// FUSED per-bucket counting sort + layer-1 aggregation (round-5 structure:
// single e2 pass, register-staged, 8-deep gathers).
// h1[n] = relu( mean_e embWl[voc_e] + embWr[x[n]] + b1 ).
__global__ __launch_bounds__(512) void k_sortagg(const int* __restrict__ bptr,
                                                 const int2* __restrict__ e2,
                                                 const int* __restrict__ x,
                                                 const float* __restrict__ embWl,
                                                 const float* __restrict__ embWr,
                                                 const float* __restrict__ b1,
                                                 int* __restrict__ rowptr,
                                                 int* __restrict__ esrc,
                                                 float* __restrict__ h1) {
    __shared__ int2 eL[ELCAP];          // 16 KB sorted edge staging
    __shared__ int sc[128];             // scan workspace (BN=96 <= 128)
    __shared__ int cur[BN];             // scatter cursors
    __shared__ int base[BN + 1];        // exclusive offsets (stable copy)
    const int b = blockIdx.x;
    const int t = threadIdx.x;
    const int r0 = bptr[b], r1 = bptr[b + 1];
    const int m = r1 - r0;

    // stage this block's edges ONCE (coalesced, up to 4/thread in registers)
    int2 ev[4];
#pragma unroll
    for (int k = 0; k < 4; k++) {
        int i = r0 + t + k * 512;
        ev[k] = (i < r1) ? e2[i] : make_int2(-1, 0);   // .x=-1 sentinel
    }
    if (t < 128) sc[t] = 0;
    __syncthreads();

    // histogram per local node (from registers)
#pragma unroll
    for (int k = 0; k < 4; k++)
        if (ev[k].x >= 0) atomicAdd(&sc[ev[k].y & 255], 1);
    __syncthreads();
    // inclusive scan (128 entries; all threads hit barriers)
    int v = (t < 128) ? sc[t] : 0;
    for (int off = 1; off < 128; off <<= 1) {
        int a = (t >= off && t < 128) ? sc[t - off] : 0;
        __syncthreads();
        if (t < 128) sc[t] += a;
        __syncthreads();
    }
    if (t < BN) {
        int excl = sc[t] - v;
        base[t] = excl;
        cur[t] = excl;
        int node = b * BN + t;
        if (node < N_NODES) rowptr[node] = r0 + excl;
        if (t == BN - 1) base[BN] = sc[t];    // = m
    }
    __syncthreads();
    // counting-sort scatter into LDS (from registers — no 2nd global pass)
#pragma unroll
    for (int k = 0; k < 4; k++) {
        if (ev[k].x >= 0) {
            int pos = atomicAdd(&cur[ev[k].y & 255], 1);
            eL[pos] = ev[k];
        }
    }
    __syncthreads();
    // CSR src write, fully coalesced from sorted LDS
    for (int i = t; i < m; i += 512)
        esrc[r0 + i] = eL[i].x;

    // per-node aggregation: 8 waves round-robin the 96 nodes; descriptors
    // come from LDS via wave-uniform broadcast reads; 8 gathers in flight.
    const int wv = t >> 6, lane = t & 63;
    const float b1v = b1[lane];
    for (int nl = wv; nl < BN; nl += 8) {
        int node = b * BN + nl;
        if (node >= N_NODES) break;
        int j0 = base[nl], j1 = base[nl + 1];
        int deg = j1 - j0;
        float s0 = 0.f, s1 = 0.f, s2 = 0.f, s3 = 0.f;
        float s4 = 0.f, s5 = 0.f, s6 = 0.f, s7 = 0.f;
        int j = j0;
        for (; j + 7 < j1; j += 8) {
            int y0 = eL[j].y,     y1 = eL[j + 1].y, y2 = eL[j + 2].y, y3 = eL[j + 3].y;
            int y4 = eL[j + 4].y, y5 = eL[j + 5].y, y6 = eL[j + 6].y, y7 = eL[j + 7].y;
            s0 += embWl[((y0 >> 8) << 6) + lane];
            s1 += embWl[((y1 >> 8) << 6) + lane];
            s2 += embWl[((y2 >> 8) << 6) + lane];
            s3 += embWl[((y3 >> 8) << 6) + lane];
            s4 += embWl[((y4 >> 8) << 6) + lane];
            s5 += embWl[((y5 >> 8) << 6) + lane];
            s6 += embWl[((y6 >> 8) << 6) + lane];
            s7 += embWl[((y7 >> 8) << 6) + lane];
        }
        for (; j + 3 < j1; j += 4) {
            int y0 = eL[j].y, y1 = eL[j + 1].y, y2 = eL[j + 2].y, y3 = eL[j + 3].y;
            s0 += embWl[((y0 >> 8) << 6) + lane];
            s1 += embWl[((y1 >> 8) << 6) + lane];
            s2 += embWl[((y2 >> 8) << 6) + lane];
            s3 += embWl[((y3 >> 8) << 6) + lane];
        }
        for (; j < j1; j++)
            s0 += embWl[((eL[j].y >> 8) << 6) + lane];
        float sum = ((s0 + s1) + (s2 + s3)) + ((s4 + s5) + (s6 + s7));
        float inv = 1.0f / fmaxf((float)deg, 1.0f);
        float self = embWr[(x[node] << 6) + lane];
        h1[((size_t)node << 6) + lane] = fmaxf(sum * inv + self + b1v, 0.0f);
    }
}

// X2b[m] = bf16[ mean_e h1[src_e] | h1[mask[m]] ], one wave per masked row,
// 8 gathers in flight.
__global__ __launch_bounds__(256) void k_x2(const int* __restrict__ mask,
                                            const int* __restrict__ rowptr,
                                            const int* __restrict__ esrc,
                                            const float* __restrict__ h1,
                                            ushort_t* __restrict__ X2b) {
    int gw = (blockIdx.x * 256 + threadIdx.x) >> 6;
    int lane = threadIdx.x & 63;
    if (gw >= N_MASK) return;
    int n = mask[gw];
    int r0 = rowptr[n], r1 = rowptr[n + 1];
    int deg = r1 - r0;
    float s0 = 0.f, s1 = 0.f, s2 = 0.f, s3 = 0.f;
    float s4 = 0.f, s5 = 0.f, s6 = 0.f, s7 = 0.f;
    for (int base = 0; base < deg; base += 64) {
        int cnt = min(64, deg - base);
        int mys = (base + lane < deg) ? esrc[r0 + base + lane] : 0;
        int t = 0;
        for (; t + 7 < cnt; t += 8) {
            int sa = __shfl(mys, t),     sb = __shfl(mys, t + 1);
            int sc = __shfl(mys, t + 2), sd = __shfl(mys, t + 3);
            int se = __shfl(mys, t + 4), sf = __shfl(mys, t + 5);
            int sg = __shfl(mys, t + 6), sh = __shfl(mys, t + 7);
            s0 += h1[((size_t)sa << 6) + lane];
            s1 += h1[((size_t)sb << 6) + lane];
            s2 += h1[((size_t)sc << 6) + lane];
            s3 += h1[((size_t)sd << 6) + lane];
            s4 += h1[((size_t)se << 6) + lane];
            s5 += h1[((size_t)sf << 6) + lane];
            s6 += h1[((size_t)sg << 6) + lane];
            s7 += h1[((size_t)sh << 6) + lane];
        }
        for (; t + 3 < cnt; t += 4) {
            int sa = __shfl(mys, t),     sb = __shfl(mys, t + 1);
            int sc = __shfl(mys, t + 2), sd = __shfl(mys, t + 3);
            s0 += h1[((size_t)sa << 6) + lane];
            s1 += h1[((size_t)sb << 6) + lane];
            s2 += h1[((size_t)sc << 6) + lane];
            s3 += h1[((size_t)sd << 6) + lane];
        }
        for (; t < cnt; t++)
            s0 += h1[((size_t)__shfl(mys, t) << 6) + lane];
    }
    float sum = ((s0 + s1) + (s2 + s3)) + ((s4 + s5) + (s6 + s7));
    float inv = 1.0f / fmaxf((float)deg, 1.0f);
    X2b[gw * 128 + lane]      = f2bf(sum * inv);
    X2b[gw * 128 + 64 + lane] = f2bf(h1[((size_t)n << 6) + lane]);
}

// out[R][c] = b2[c] + X2[R] . W2T[c]   via bf16 MFMA, fp32 accumulate.
__global__ __launch_bounds__(256) void k_gemm2_mfma(const ushort_t* __restrict__ X2b,
                                                    const ushort_t* __restrict__ W2T,
                                                    const float* __restrict__ bias,
                                                    float* __restrict__ out,
                                                    int M) {
    __shared__ ushort_t As[64 * 144];
    __shared__ ushort_t Bs[64 * 144];
    const int tid  = threadIdx.x;
    const int row0 = blockIdx.x * 64;
    const int col0 = blockIdx.y * 64;

#pragma unroll
    for (int i = 0; i < 4; i++) {
        int idx = i * 256 + tid;
        int r = idx >> 4, ch = idx & 15;
        int R = row0 + r;
        short8 v = {0, 0, 0, 0, 0, 0, 0, 0};
        if (R < M) v = *(const short8*)(X2b + (size_t)R * 128 + ch * 8);
        *(short8*)(As + r * 144 + ch * 8) = v;
    }
#pragma unroll
    for (int i = 0; i < 4; i++) {
        int idx = i * 256 + tid;
        int r = idx >> 4, ch = idx & 15;
        *(short8*)(Bs + r * 144 + ch * 8) =
            *(const short8*)(W2T + (size_t)(col0 + r) * 128 + ch * 8);
    }
    __syncthreads();

    const int lane = tid & 63;
    const int wv   = tid >> 6;
    const int wr = wv >> 1, wc = wv & 1;
    const int l15 = lane & 15, q = lane >> 4;

    f32x4 acc[2][2] = {};
    const ushort_t* Abase = As + (wr * 32 + l15) * 144 + q * 8;
    const ushort_t* Bbase = Bs + (wc * 32 + l15) * 144 + q * 8;

#pragma unroll
    for (int ks = 0; ks < 4; ks++) {
        short8 a0 = *(const short8*)(Abase + ks * 32);
        short8 a1 = *(const short8*)(Abase + 16 * 144 + ks * 32);
        short8 b0 = *(const short8*)(Bbase + ks * 32);
        short8 b1 = *(const short8*)(Bbase + 16 * 144 + ks * 32);
        acc[0][0] = __builtin_amdgcn_mfma_f32_16x16x32_bf16(a0, b0, acc[0][0], 0, 0, 0);
        acc[0][1] = __builtin_amdgcn_mfma_f32_16x16x32_bf16(a0, b1, acc[0][1], 0, 0, 0);
        acc[1][0] = __builtin_amdgcn_mfma_f32_16x16x32_bf16(a1, b0, acc[1][0], 0, 0, 0);
        acc[1][1] = __builtin_amdgcn_mfma_f32_16x16x32_bf16(a1, b1, acc[1][1], 0, 0, 0);
    }

    // C/D layout: col = lane&15, row = (lane>>4)*4 + reg  [verified m89/m91]
#pragma unroll
    for (int ni = 0; ni < 2; ni++) {
        int c_ = col0 + wc * 32 + ni * 16 + l15;
        float bv = bias[c_];
#pragma unroll
        for (int mi = 0; mi < 2; mi++) {
#pragma unroll
            for (int reg = 0; reg < 4; reg++) {
                int r_ = row0 + wr * 32 + mi * 16 + q * 4 + reg;
                if (r_ < M) out[(size_t)r_ * VOCAB + c_] = acc[mi][ni][reg] + bv;
            }
        }
    }
}

__global__ __launch_bounds__(256) void k_logsoftmax(float* __restrict__ out) {
    const int row = blockIdx.x;
    float4* p4 = (float4*)(out + (size_t)row * VOCAB);
    const int tid = threadIdx.x;
    float4 v[2];
    float m = -INFINITY;
#pragma unroll
    for (int i = 0; i < 2; i++) {
        v[i] = p4[tid + i * 256];
        m = fmaxf(m, fmaxf(fmaxf(v[i].x, v[i].y), fmaxf(v[i].z, v[i].w)));
    }
#pragma unroll
    for (int off = 1; off < 64; off <<= 1) m = fmaxf(m, __shfl_xor(m, off));
    __shared__ float redm[4];
    __shared__ float reds[4];
    int wave = tid >> 6;
    if ((tid & 63) == 0) redm[wave] = m;
    __syncthreads();
    m = fmaxf(fmaxf(redm[0], redm[1]), fmaxf(redm[2], redm[3]));
    float s = 0.0f;
#pragma unroll
    for (int i = 0; i < 2; i++)
        s += expf(v[i].x - m) + expf(v[i].y - m) + expf(v[i].z - m) + expf(v[i].w - m);
#pragma unroll
    for (int off = 1; off < 64; off <<= 1) s += __shfl_xor(s, off);
    if ((tid & 63) == 0) reds[wave] = s;
    __syncthreads();
    s = reds[0] + reds[1] + reds[2] + reds[3];
    float L = m + logf(s);
#pragma unroll
    for (int i = 0; i < 2; i++) {
        float4 o = v[i];
        o.x -= L; o.y -= L; o.z -= L; o.w -= L;
        p4[tid + i * 256] = o;
    }
}

extern "C" void kernel_launch(void* const* d_in, const int* in_sizes, int n_in,
                              void* d_out, int out_size, void* d_ws, size_t ws_size,
                              hipStream_t stream) {
    const int*   x    = (const int*)d_in[0];
    const int*   ei   = (const int*)d_in[1];
    const int*   src  = ei;
    const int*   dst  = ei + N_EDGES;
    const int*   mask = (const int*)d_in[2];
    const float* emb  = (const float*)d_in[3];
    const float* Wl1  = (const float*)d_in[4];
    const float* bl1  = (const float*)d_in[5];
    const float* Wr1  = (const float*)d_in[6];
    const float* Wl2  = (const float*)d_in[7];
    const float* bl2  = (const float*)d_in[8];
    const float* Wr2  = (const float*)d_in[9];
    float* out = (float*)d_out;

    char* ws = (char*)d_ws;
    float*    h1     = (float*)(ws + H1_OFF);
    int*      esrc   = (int*)(ws + ESRC_OFF);
    int2*     e2     = (int2*)(ws + E2_OFF);
    float*    embWl  = (float*)(ws + EWL_OFF);
    float*    embWr  = (float*)(ws + EWR_OFF);
    ushort_t* W2T    = (ushort_t*)(ws + W2T_OFF);
    ushort_t* X2b    = (ushort_t*)(ws + X2B_OFF);
    int*      rowptr = (int*)(ws + ROWPTR_OFF);
    int*      bcnt   = (int*)(ws + BCNT_OFF);
    int*      bptr   = (int*)(ws + BPTR_OFF);
    ushort_t* mat    = (ushort_t*)(ws + MAT_OFF);

    // ---- tables + per-chunk histograms in ONE launch (all inputs ready) ----
    k_prep<<<1088 + NCH, 256, 0, stream>>>(emb, Wl1, Wr1, Wl2, Wr2, dst,
                                           embWl, embWr, W2T, mat);

    // ---- deterministic count-matrix partition (no global atomics) ----
    k_mscan   <<<NBKT, 512, 0, stream>>>(mat, bcnt);
    k_bscan   <<<1, 1024, 0, stream>>>(bcnt, bptr, rowptr);
    k_scatter3<<<NCH, 256, 0, stream>>>(src, dst, x, mat, bptr, e2);

    // ---- fused per-bucket sort + layer-1 aggregation (single e2 pass) ----
    k_sortagg<<<NBKT, 512, 0, stream>>>(bptr, e2, x, embWl, embWr, bl1, rowptr, esrc, h1);

    // ---- layer 2: masked-row gather -> bf16 X2, MFMA GEMM, log_softmax ----
    k_x2<<<(N_MASK * 64 + 255) / 256, 256, 0, stream>>>(mask, rowptr, esrc, h1, X2b);
    dim3 g2((N_MASK + 63) / 64, VOCAB / 64);
    k_gemm2_mfma<<<g2, 256, 0, stream>>>(X2b, W2T, bl2, out, N_MASK);

    k_logsoftmax<<<N_MASK, 256, 0, stream>>>(out);
}